// Round 1
// baseline (203.653 us; speedup 1.0000x reference)
//
#include <hip/hip_runtime.h>
#include <hip/hip_bf16.h>
#include <stdint.h>

typedef unsigned short u16;
typedef __bf16 bf16x8 __attribute__((ext_vector_type(8)));
typedef float f32x4 __attribute__((ext_vector_type(4)));

#define B_ 2
#define T_ 2048
#define C_ 1024
#define H_ 16
#define HD 64
#define M_ (B_ * T_)   // 4096
#define N3 (3 * C_)    // 3072

__device__ __forceinline__ float bf2f(u16 u) {
  return __uint_as_float(((unsigned int)u) << 16);
}
__device__ __forceinline__ u16 f2bf(float f) {
  unsigned int u = __float_as_uint(f);
  u += 0x7FFF + ((u >> 16) & 1);   // round-to-nearest-even (finite inputs only)
  return (u16)(u >> 16);
}

union U16x8 { uint4 v; u16 u[8]; };

// LDS fragment read: all tiles are [row][64 bf16] = 128B rows, XOR-swizzled
// byte ^= (row&7)<<4 to break the 16-way bank conflict (G4).
__device__ __forceinline__ bf16x8 ldsAfrag(const char* base, int row, int kbyte) {
  int off = (row * 128 + kbyte) ^ ((row & 7) << 4);
  uint4 t = *reinterpret_cast<const uint4*>(base + off);
  return __builtin_bit_cast(bf16x8, t);
}

// ---------------- f32 -> bf16 convert ----------------
__global__ void cvt_bf16(const float* __restrict__ src, u16* __restrict__ dst, int n4) {
  int i = blockIdx.x * blockDim.x + threadIdx.x;
  int stride = gridDim.x * blockDim.x;
  for (; i < n4; i += stride) {
    float4 v = reinterpret_cast<const float4*>(src)[i];
    uint2 o;
    o.x = (unsigned)f2bf(v.x) | ((unsigned)f2bf(v.y) << 16);
    o.y = (unsigned)f2bf(v.z) | ((unsigned)f2bf(v.w) << 16);
    reinterpret_cast<uint2*>(dst)[i] = o;
  }
}

// ---------------- RoPE cos/sin tables [T][32] f32 ----------------
__global__ void rope_tables_kernel(float* __restrict__ cosT, float* __restrict__ sinT) {
  int t = blockIdx.x;
  int i = threadIdx.x;  // 0..31
  float inv = powf(10000.0f, -(float)i * (1.0f / 32.0f));
  float f = (float)t * inv;
  cosT[t * 32 + i] = cosf(f);
  sinT[t * 32 + i] = sinf(f);
}

// ---------------- bf16 GEMM, both operands K-major (B^T input) ----------------
// C[m][n] = sum_k A[m][k] * Bw[n][k].  128x128 tile, BK=64, 4 waves (2x2 of 64x64).
template <bool OUT_F32>
__global__ __launch_bounds__(256) void gemm_bt(const u16* __restrict__ A,
                                               const u16* __restrict__ Bw,
                                               void* __restrict__ Cout,
                                               int M, int N, int K) {
  __shared__ uint4 ldsbuf[2048];  // 32KB: As 16KB + Bs 16KB
  char* As = (char*)ldsbuf;
  char* Bs = (char*)ldsbuf + 16384;
  const int tid = threadIdx.x;
  const int lane = tid & 63;
  const int wv = tid >> 6;
  const int wr = wv >> 1, wc = wv & 1;
  const int lrow = lane & 15, lgrp = lane >> 4;
  const long m0 = (long)blockIdx.x * 128, n0 = (long)blockIdx.y * 128;
  const int srow = tid >> 3, sc = tid & 7;  // staging: 32 rows/pass, 8x16B cols
  f32x4 acc[4][4] = {};
  for (int k0 = 0; k0 < K; k0 += 64) {
    __syncthreads();
#pragma unroll
    for (int p = 0; p < 4; ++p) {
      int row = srow + p * 32;
      uint4 va = *reinterpret_cast<const uint4*>(A + (m0 + row) * K + k0 + sc * 8);
      *reinterpret_cast<uint4*>(As + ((row * 128 + sc * 16) ^ ((row & 7) << 4))) = va;
      uint4 vb = *reinterpret_cast<const uint4*>(Bw + (n0 + row) * K + k0 + sc * 8);
      *reinterpret_cast<uint4*>(Bs + ((row * 128 + sc * 16) ^ ((row & 7) << 4))) = vb;
    }
    __syncthreads();
#pragma unroll
    for (int ks = 0; ks < 2; ++ks) {
      bf16x8 af[4], bfr[4];
#pragma unroll
      for (int i = 0; i < 4; ++i) {
        af[i]  = ldsAfrag(As, wr * 64 + i * 16 + lrow, ks * 64 + lgrp * 16);
        bfr[i] = ldsAfrag(Bs, wc * 64 + i * 16 + lrow, ks * 64 + lgrp * 16);
      }
#pragma unroll
      for (int i = 0; i < 4; ++i)
#pragma unroll
        for (int j = 0; j < 4; ++j)
          acc[i][j] = __builtin_amdgcn_mfma_f32_16x16x32_bf16(af[i], bfr[j], acc[i][j], 0, 0, 0);
    }
  }
  // epilogue: C/D layout col=lane&15, row=(lane>>4)*4+r (m89-verified)
#pragma unroll
  for (int i = 0; i < 4; ++i)
#pragma unroll
    for (int j = 0; j < 4; ++j) {
      long r0 = m0 + wr * 64 + i * 16 + lgrp * 4;
      long c  = n0 + wc * 64 + j * 16 + lrow;
#pragma unroll
      for (int r = 0; r < 4; ++r) {
        float v = acc[i][j][r];
        if (OUT_F32)
          ((float*)Cout)[(r0 + r) * N + c] = v;
        else
          ((u16*)Cout)[(r0 + r) * N + c] = f2bf(v);
      }
    }
}

// ---------------- RoPE apply + reshape to [BH][T][64] (Q,K) and [BH][64][T] (V^T) ----
__global__ __launch_bounds__(256) void rope_reshape(const u16* __restrict__ qkv,
                                                    const float* __restrict__ cosT,
                                                    const float* __restrict__ sinT,
                                                    u16* __restrict__ Q,
                                                    u16* __restrict__ K,
                                                    u16* __restrict__ Vt) {
  __shared__ u16 Vs[64][80];  // padded rows (160B) keep uint4 writes aligned
  const int tid = threadIdx.x;
  const int tblk = blockIdx.x, bh = blockIdx.y;
  const int b = bh >> 4, h = bh & 15;
  const int tl = tid >> 2, quar = tid & 3;
  const int t = tblk * 64 + tl;
  const u16* rowp = qkv + ((size_t)(b * T_ + t)) * N3 + h * HD;
  const int d0 = quar * 8;  // handles pair (d0..d0+7, d0+32..d0+39)
  float cs[8], sn[8];
#pragma unroll
  for (int j = 0; j < 8; ++j) {
    cs[j] = cosT[t * 32 + d0 + j];
    sn[j] = sinT[t * 32 + d0 + j];
  }
#pragma unroll
  for (int part = 0; part < 2; ++part) {  // 0=q, 1=k
    const u16* p = rowp + part * C_;
    U16x8 x1, x2, o1, o2;
    x1.v = *reinterpret_cast<const uint4*>(p + d0);
    x2.v = *reinterpret_cast<const uint4*>(p + d0 + 32);
#pragma unroll
    for (int j = 0; j < 8; ++j) {
      float a = bf2f(x1.u[j]), c2 = bf2f(x2.u[j]);
      o1.u[j] = f2bf(a * cs[j] - c2 * sn[j]);   // d<32: rot = -x[d+32]
      o2.u[j] = f2bf(c2 * cs[j] + a * sn[j]);   // d>=32: rot = x[d-32], same freq
    }
    u16* dst = (part ? K : Q) + ((size_t)bh * T_ + t) * HD;
    *reinterpret_cast<uint4*>(dst + d0) = o1.v;
    *reinterpret_cast<uint4*>(dst + d0 + 32) = o2.v;
  }
  // V: stage tile then write transposed rows (coalesced 32B stores)
  const u16* pv = rowp + 2 * C_;
#pragma unroll
  for (int c = 0; c < 2; ++c) {
    int d = quar * 16 + c * 8;
    *reinterpret_cast<uint4*>(&Vs[tl][d]) = *reinterpret_cast<const uint4*>(pv + d);
  }
  __syncthreads();
  const int d = tid >> 2, tq = tid & 3;
  U16x8 a, bv;
#pragma unroll
  for (int j = 0; j < 8; ++j) a.u[j] = Vs[tq * 16 + j][d];
#pragma unroll
  for (int j = 0; j < 8; ++j) bv.u[j] = Vs[tq * 16 + 8 + j][d];
  u16* dstv = Vt + ((size_t)bh * HD + d) * T_ + tblk * 64 + tq * 16;
  *reinterpret_cast<uint4*>(dstv) = a.v;
  *reinterpret_cast<uint4*>(dstv + 8) = bv.v;
}

// ---------------- causal flash attention ----------------
// Q,K: [BH][T][64] bf16 (roped), Vt: [BH][64][T] bf16, O: [B][T][C] bf16.
// Block: 128 q rows, 4 waves x 32 rows. KBLK=64. Online softmax per §B recipe.
__global__ __launch_bounds__(256) void attn_fwd(const u16* __restrict__ Q,
                                                const u16* __restrict__ K,
                                                const u16* __restrict__ Vt,
                                                u16* __restrict__ O) {
  __shared__ uint4 ldsK[512];   // 8KB  [64 key][64 d]
  __shared__ uint4 ldsV[512];   // 8KB  [64 d][64 key]
  __shared__ uint4 ldsP[1024];  // 16KB: per-wave 4KB [32 q][64 key]
  char* Ks = (char*)ldsK;
  char* Vs = (char*)ldsV;
  const int tid = threadIdx.x;
  const int lane = tid & 63, wv = tid >> 6;
  const int lrow = lane & 15, lgrp = lane >> 4;
  char* Ps = (char*)ldsP + wv * 4096;
  const int q0 = blockIdx.x * 128;
  const int bh = blockIdx.y;
  const int b = bh >> 4, h = bh & 15;
  const u16* Qh = Q + (size_t)bh * T_ * HD;
  const u16* Kh = K + (size_t)bh * T_ * HD;
  const u16* Vh = Vt + (size_t)bh * HD * T_;

  // Q fragments held in registers for the whole block
  bf16x8 qf[2][2];
#pragma unroll
  for (int m = 0; m < 2; ++m)
#pragma unroll
    for (int ks = 0; ks < 2; ++ks) {
      int t = q0 + wv * 32 + m * 16 + lrow;
      uint4 tmp = *reinterpret_cast<const uint4*>(Qh + (size_t)t * HD + ks * 32 + lgrp * 8);
      qf[m][ks] = __builtin_bit_cast(bf16x8, tmp);
    }

  f32x4 o[2][4] = {};
  float mrun[2][4], lrun[2][4];
#pragma unroll
  for (int m = 0; m < 2; ++m)
#pragma unroll
    for (int r = 0; r < 4; ++r) { mrun[m][r] = -__builtin_inff(); lrun[m][r] = 0.f; }

  const int nk = (q0 + 128) / 64;
  const int srow = tid >> 2, scc = tid & 3;
  for (int kt = 0; kt < nk; ++kt) {
    const int k0 = kt * 64;
    __syncthreads();
#pragma unroll
    for (int p = 0; p < 2; ++p) {
      int c = scc * 2 + p;  // 16B chunk 0..7
      uint4 vk = *reinterpret_cast<const uint4*>(Kh + (size_t)(k0 + srow) * HD + c * 8);
      *reinterpret_cast<uint4*>(Ks + ((srow * 128 + c * 16) ^ ((srow & 7) << 4))) = vk;
      uint4 vv = *reinterpret_cast<const uint4*>(Vh + (size_t)srow * T_ + k0 + c * 8);
      *reinterpret_cast<uint4*>(Vs + ((srow * 128 + c * 16) ^ ((srow & 7) << 4))) = vv;
    }
    __syncthreads();

    // S = Q K^T  (A=Q rows, B from K tile: col=key, k=d — contiguous in d)
    f32x4 s[2][4] = {};
#pragma unroll
    for (int ks = 0; ks < 2; ++ks) {
      bf16x8 bk[4];
#pragma unroll
      for (int n = 0; n < 4; ++n) bk[n] = ldsAfrag(Ks, n * 16 + lrow, ks * 64 + lgrp * 16);
#pragma unroll
      for (int m = 0; m < 2; ++m)
#pragma unroll
        for (int n = 0; n < 4; ++n)
          s[m][n] = __builtin_amdgcn_mfma_f32_16x16x32_bf16(qf[m][ks], bk[n], s[m][n], 0, 0, 0);
    }

#pragma unroll
    for (int m = 0; m < 2; ++m) {
      const int qg = q0 + wv * 32 + m * 16 + lgrp * 4;  // + r
      // scale + causal mask
#pragma unroll
      for (int n = 0; n < 4; ++n) {
        int kg = k0 + n * 16 + lrow;
#pragma unroll
        for (int r = 0; r < 4; ++r) {
          float v = s[m][n][r] * 0.125f;
          s[m][n][r] = (kg <= qg + r) ? v : -__builtin_inff();
        }
      }
#pragma unroll
      for (int r = 0; r < 4; ++r) {
        float tm = fmaxf(fmaxf(s[m][0][r], s[m][1][r]), fmaxf(s[m][2][r], s[m][3][r]));
#pragma unroll
        for (int msk = 1; msk < 16; msk <<= 1) tm = fmaxf(tm, __shfl_xor(tm, msk, 64));
        float nm = fmaxf(mrun[m][r], tm);
        float alpha = __expf(mrun[m][r] - nm);  // first tile: exp(-inf)=0
        mrun[m][r] = nm;
        float psum = 0.f;
#pragma unroll
        for (int n = 0; n < 4; ++n) {
          float p = __expf(s[m][n][r] - nm);
          s[m][n][r] = p;
          psum += p;
        }
#pragma unroll
        for (int msk = 1; msk < 16; msk <<= 1) psum += __shfl_xor(psum, msk, 64);
        lrun[m][r] = lrun[m][r] * alpha + psum;
#pragma unroll
        for (int dn = 0; dn < 4; ++dn) o[m][dn][r] *= alpha;
      }
      // P (C-layout) -> per-wave LDS as bf16 for the PV A-operand
#pragma unroll
      for (int n = 0; n < 4; ++n)
#pragma unroll
        for (int r = 0; r < 4; ++r) {
          int row = m * 16 + lgrp * 4 + r;
          int off = (row * 128 + (n * 16 + lrow) * 2) ^ ((row & 7) << 4);
          *reinterpret_cast<u16*>(Ps + off) = f2bf(s[m][n][r]);
        }
    }
    __syncthreads();  // orders Ps writes (cross-lane) before A-frag reads

    // O += P * V   (B from Vt tile: col=d, k=key — contiguous in key)
#pragma unroll
    for (int ks = 0; ks < 2; ++ks) {
      bf16x8 pa[2], bv[4];
#pragma unroll
      for (int m = 0; m < 2; ++m) pa[m] = ldsAfrag(Ps, m * 16 + lrow, ks * 64 + lgrp * 16);
#pragma unroll
      for (int dn = 0; dn < 4; ++dn) bv[dn] = ldsAfrag(Vs, dn * 16 + lrow, ks * 64 + lgrp * 16);
#pragma unroll
      for (int m = 0; m < 2; ++m)
#pragma unroll
        for (int dn = 0; dn < 4; ++dn)
          o[m][dn] = __builtin_amdgcn_mfma_f32_16x16x32_bf16(pa[m], bv[dn], o[m][dn], 0, 0, 0);
    }
  }

  // epilogue: divide by row sum, write O[b][t][h*64+d]
#pragma unroll
  for (int m = 0; m < 2; ++m)
#pragma unroll
    for (int r = 0; r < 4; ++r) {
      float inv = 1.0f / lrun[m][r];
      int t = q0 + wv * 32 + m * 16 + lgrp * 4 + r;
#pragma unroll
      for (int dn = 0; dn < 4; ++dn) {
        int c = h * HD + dn * 16 + lrow;
        O[((size_t)(b * T_ + t)) * C_ + c] = f2bf(o[m][dn][r] * inv);
      }
    }
}

// ---------------- launch ----------------
extern "C" void kernel_launch(void* const* d_in, const int* in_sizes, int n_in,
                              void* d_out, int out_size, void* d_ws, size_t ws_size,
                              hipStream_t stream) {
  const float* x  = (const float*)d_in[0];
  const float* wa = (const float*)d_in[1];
  const float* wp = (const float*)d_in[2];
  float* out = (float*)d_out;
  char* ws = (char*)d_ws;
  size_t off = 0;
  auto alloc = [&](size_t bytes) {
    char* p = ws + off;
    off += (bytes + 255) & ~(size_t)255;
    return p;
  };
  u16* xb   = (u16*)alloc((size_t)M_ * C_ * 2);          // 8MB
  u16* wab  = (u16*)alloc((size_t)N3 * C_ * 2);          // 6MB
  u16* wpb  = (u16*)alloc((size_t)C_ * C_ * 2);          // 2MB
  u16* qkvb = (u16*)alloc((size_t)M_ * N3 * 2);          // 24MB
  u16* Qb   = (u16*)alloc((size_t)B_ * H_ * T_ * HD * 2);// 8MB
  u16* Kb   = (u16*)alloc((size_t)B_ * H_ * T_ * HD * 2);// 8MB
  u16* Vtb  = (u16*)alloc((size_t)B_ * H_ * T_ * HD * 2);// 8MB
  u16* Ob   = (u16*)alloc((size_t)M_ * C_ * 2);          // 8MB
  float* cosT = (float*)alloc((size_t)T_ * 32 * 4);
  float* sinT = (float*)alloc((size_t)T_ * 32 * 4);
  (void)in_sizes; (void)n_in; (void)out_size; (void)ws_size;

  cvt_bf16<<<1024, 256, 0, stream>>>(x, xb, M_ * C_ / 4);
  cvt_bf16<<<1024, 256, 0, stream>>>(wa, wab, N3 * C_ / 4);
  cvt_bf16<<<512, 256, 0, stream>>>(wp, wpb, C_ * C_ / 4);
  rope_tables_kernel<<<T_, 32, 0, stream>>>(cosT, sinT);
  gemm_bt<false><<<dim3(M_ / 128, N3 / 128), 256, 0, stream>>>(xb, wab, qkvb, M_, N3, C_);
  rope_reshape<<<dim3(T_ / 64, B_ * H_), 256, 0, stream>>>(qkvb, cosT, sinT, Qb, Kb, Vtb);
  attn_fwd<<<dim3(T_ / 128, B_ * H_), 256, 0, stream>>>(Qb, Kb, Vtb, Ob);
  gemm_bt<true><<<dim3(M_ / 128, C_ / 128), 256, 0, stream>>>(Ob, wpb, out, M_, C_, C_);
}

// Round 2
// 145.055 us; speedup vs baseline: 1.4040x; 1.4040x over previous
//
#include <hip/hip_runtime.h>
#include <hip/hip_bf16.h>
#include <stdint.h>

typedef unsigned short u16;
typedef __bf16 bf16x8 __attribute__((ext_vector_type(8)));
typedef float f32x4 __attribute__((ext_vector_type(4)));

#define B_ 2
#define T_ 2048
#define C_ 1024
#define H_ 16
#define HD 64
#define M_ (B_ * T_)   // 4096
#define N3 (3 * C_)    // 3072

__device__ __forceinline__ float bf2f(u16 u) {
  return __uint_as_float(((unsigned int)u) << 16);
}
__device__ __forceinline__ u16 f2bf(float f) {
  unsigned int u = __float_as_uint(f);
  u += 0x7FFF + ((u >> 16) & 1);   // round-to-nearest-even (finite inputs only)
  return (u16)(u >> 16);
}

union U16x8 { uint4 v; u16 u[8]; };

// LDS fragment read, 128B rows: off = row*128 + kbyte, XOR-swizzled (G4).
__device__ __forceinline__ bf16x8 ldsAfrag(const char* base, int row, int kbyte) {
  int off = (row * 128 + kbyte) ^ ((row & 7) << 4);
  uint4 t = *reinterpret_cast<const uint4*>(base + off);
  return __builtin_bit_cast(bf16x8, t);
}
// 256B rows variant (128-key tiles)
__device__ __forceinline__ bf16x8 ldsAfrag256(const char* base, int row, int kbyte) {
  int off = (row * 256 + kbyte) ^ ((row & 7) << 4);
  uint4 t = *reinterpret_cast<const uint4*>(base + off);
  return __builtin_bit_cast(bf16x8, t);
}

// ---------------- f32 -> bf16 convert ----------------
__global__ void cvt_bf16(const float* __restrict__ src, u16* __restrict__ dst, int n4) {
  int i = blockIdx.x * blockDim.x + threadIdx.x;
  int stride = gridDim.x * blockDim.x;
  for (; i < n4; i += stride) {
    float4 v = reinterpret_cast<const float4*>(src)[i];
    uint2 o;
    o.x = (unsigned)f2bf(v.x) | ((unsigned)f2bf(v.y) << 16);
    o.y = (unsigned)f2bf(v.z) | ((unsigned)f2bf(v.w) << 16);
    reinterpret_cast<uint2*>(dst)[i] = o;
  }
}

// ---------------- RoPE cos/sin tables [T][32] f32 ----------------
__global__ void rope_tables_kernel(float* __restrict__ cosT, float* __restrict__ sinT) {
  int t = blockIdx.x;
  int i = threadIdx.x;  // 0..31
  float inv = powf(10000.0f, -(float)i * (1.0f / 32.0f));
  float f = (float)t * inv;
  cosT[t * 32 + i] = cosf(f);
  sinT[t * 32 + i] = sinf(f);
}

// ---------------- bf16 GEMM, both operands K-major (B^T input) ----------------
template <bool OUT_F32>
__global__ __launch_bounds__(256) void gemm_bt(const u16* __restrict__ A,
                                               const u16* __restrict__ Bw,
                                               void* __restrict__ Cout,
                                               int M, int N, int K) {
  __shared__ uint4 ldsbuf[2048];  // 32KB: As 16KB + Bs 16KB
  char* As = (char*)ldsbuf;
  char* Bs = (char*)ldsbuf + 16384;
  const int tid = threadIdx.x;
  const int lane = tid & 63;
  const int wv = tid >> 6;
  const int wr = wv >> 1, wc = wv & 1;
  const int lrow = lane & 15, lgrp = lane >> 4;
  const long m0 = (long)blockIdx.x * 128, n0 = (long)blockIdx.y * 128;
  const int srow = tid >> 3, sc = tid & 7;
  f32x4 acc[4][4] = {};
  for (int k0 = 0; k0 < K; k0 += 64) {
    __syncthreads();
#pragma unroll
    for (int p = 0; p < 4; ++p) {
      int row = srow + p * 32;
      uint4 va = *reinterpret_cast<const uint4*>(A + (m0 + row) * K + k0 + sc * 8);
      *reinterpret_cast<uint4*>(As + ((row * 128 + sc * 16) ^ ((row & 7) << 4))) = va;
      uint4 vb = *reinterpret_cast<const uint4*>(Bw + (n0 + row) * K + k0 + sc * 8);
      *reinterpret_cast<uint4*>(Bs + ((row * 128 + sc * 16) ^ ((row & 7) << 4))) = vb;
    }
    __syncthreads();
#pragma unroll
    for (int ks = 0; ks < 2; ++ks) {
      bf16x8 af[4], bfr[4];
#pragma unroll
      for (int i = 0; i < 4; ++i) {
        af[i]  = ldsAfrag(As, wr * 64 + i * 16 + lrow, ks * 64 + lgrp * 16);
        bfr[i] = ldsAfrag(Bs, wc * 64 + i * 16 + lrow, ks * 64 + lgrp * 16);
      }
#pragma unroll
      for (int i = 0; i < 4; ++i)
#pragma unroll
        for (int j = 0; j < 4; ++j)
          acc[i][j] = __builtin_amdgcn_mfma_f32_16x16x32_bf16(af[i], bfr[j], acc[i][j], 0, 0, 0);
    }
  }
#pragma unroll
  for (int i = 0; i < 4; ++i)
#pragma unroll
    for (int j = 0; j < 4; ++j) {
      long r0 = m0 + wr * 64 + i * 16 + lgrp * 4;
      long c  = n0 + wc * 64 + j * 16 + lrow;
#pragma unroll
      for (int r = 0; r < 4; ++r) {
        float v = acc[i][j][r];
        if (OUT_F32)
          ((float*)Cout)[(r0 + r) * N + c] = v;
        else
          ((u16*)Cout)[(r0 + r) * N + c] = f2bf(v);
      }
    }
}

// ---------------- RoPE apply + reshape to [BH][T][64] (Q,K) and [BH][64][T] (V^T) ----
__global__ __launch_bounds__(256) void rope_reshape(const u16* __restrict__ qkv,
                                                    const float* __restrict__ cosT,
                                                    const float* __restrict__ sinT,
                                                    u16* __restrict__ Q,
                                                    u16* __restrict__ K,
                                                    u16* __restrict__ Vt) {
  __shared__ u16 Vs[64][80];
  const int tid = threadIdx.x;
  const int tblk = blockIdx.x, bh = blockIdx.y;
  const int b = bh >> 4, h = bh & 15;
  const int tl = tid >> 2, quar = tid & 3;
  const int t = tblk * 64 + tl;
  const u16* rowp = qkv + ((size_t)(b * T_ + t)) * N3 + h * HD;
  const int d0 = quar * 8;
  float cs[8], sn[8];
#pragma unroll
  for (int j = 0; j < 8; ++j) {
    cs[j] = cosT[t * 32 + d0 + j];
    sn[j] = sinT[t * 32 + d0 + j];
  }
#pragma unroll
  for (int part = 0; part < 2; ++part) {
    const u16* p = rowp + part * C_;
    U16x8 x1, x2, o1, o2;
    x1.v = *reinterpret_cast<const uint4*>(p + d0);
    x2.v = *reinterpret_cast<const uint4*>(p + d0 + 32);
#pragma unroll
    for (int j = 0; j < 8; ++j) {
      float a = bf2f(x1.u[j]), c2 = bf2f(x2.u[j]);
      o1.u[j] = f2bf(a * cs[j] - c2 * sn[j]);
      o2.u[j] = f2bf(c2 * cs[j] + a * sn[j]);
    }
    u16* dst = (part ? K : Q) + ((size_t)bh * T_ + t) * HD;
    *reinterpret_cast<uint4*>(dst + d0) = o1.v;
    *reinterpret_cast<uint4*>(dst + d0 + 32) = o2.v;
  }
  const u16* pv = rowp + 2 * C_;
#pragma unroll
  for (int c = 0; c < 2; ++c) {
    int d = quar * 16 + c * 8;
    *reinterpret_cast<uint4*>(&Vs[tl][d]) = *reinterpret_cast<const uint4*>(pv + d);
  }
  __syncthreads();
  const int d = tid >> 2, tq = tid & 3;
  U16x8 a, bv;
#pragma unroll
  for (int j = 0; j < 8; ++j) a.u[j] = Vs[tq * 16 + j][d];
#pragma unroll
  for (int j = 0; j < 8; ++j) bv.u[j] = Vs[tq * 16 + 8 + j][d];
  u16* dstv = Vt + ((size_t)bh * HD + d) * T_ + tblk * 64 + tq * 16;
  *reinterpret_cast<uint4*>(dstv) = a.v;
  *reinterpret_cast<uint4*>(dstv + 8) = bv.v;
}

// ---------------- causal flash attention v2 ----------------
// Q,K: [BH][T][64] bf16 (roped), Vt: [BH][64][T] bf16, O: [B][T][C] bf16.
// 4 waves x 16 q-rows (QBLK=64). KBLK=128. Paired units (u, 31-u) -> 17 iters/block.
// Per-wave P buffer (no barrier for P round-trip). Grid (16, 32) = 2 blocks/CU.
__global__ __launch_bounds__(256) void attn_fwd2(const u16* __restrict__ Q,
                                                 const u16* __restrict__ K,
                                                 const u16* __restrict__ Vt,
                                                 u16* __restrict__ O) {
  __shared__ char lds[49152];           // Ks 16KB + Vs 16KB + Ps 4x4KB
  char* Ks = lds;                       // [128 keys][64 d]  rows 128B, swizzled
  char* Vs = lds + 16384;               // [64 d][128 keys]  rows 256B, swizzled
  const int tid = threadIdx.x;
  const int lane = tid & 63, wv = tid >> 6;
  const int lrow = lane & 15, lgrp = lane >> 4;
  char* Ps = lds + 32768 + wv * 4096;   // [16 q][128 keys] rows 256B, swizzled
  const int bh = blockIdx.y;
  const int b = bh >> 4, h = bh & 15;
  const u16* Qh = Q + (size_t)bh * T_ * HD;
  const u16* Kh = K + (size_t)bh * T_ * HD;
  const u16* Vh = Vt + (size_t)bh * HD * T_;
  // staging: K tile 1024 chunks (row=chunk>>3, c=chunk&7), Vt tile 1024 (d=chunk>>4, kc=chunk&15)
  const int krow = tid >> 3, kcol = tid & 7;
  const int vd = tid >> 4, vkc = tid & 15;

#pragma unroll
  for (int uu = 0; uu < 2; ++uu) {
    const int unit = uu ? (31 - (int)blockIdx.x) : (int)blockIdx.x;
    const int qs = unit * 64;
    // Q fragments (A-operand: row = lane&15, k = lgrp*8+j)
    bf16x8 qf[2];
#pragma unroll
    for (int ks = 0; ks < 2; ++ks) {
      uint4 t4 = *reinterpret_cast<const uint4*>(
          Qh + (size_t)(qs + wv * 16 + lrow) * HD + ks * 32 + lgrp * 8);
      qf[ks] = __builtin_bit_cast(bf16x8, t4);
    }
    f32x4 o[4] = {};
    float mrun[4], lrun[4];
#pragma unroll
    for (int r = 0; r < 4; ++r) { mrun[r] = -__builtin_inff(); lrun[r] = 0.f; }

    const int niter = (unit >> 1) + 1;
    for (int kt = 0; kt < niter; ++kt) {
      const int k0 = kt * 128;
      __syncthreads();  // prev-iter PV reads done before restage
      {
#pragma unroll
        for (int p = 0; p < 4; ++p) {
          int row = krow + p * 32;
          uint4 v = *reinterpret_cast<const uint4*>(Kh + (size_t)(k0 + row) * HD + kcol * 8);
          *reinterpret_cast<uint4*>(Ks + ((row * 128 + kcol * 16) ^ ((row & 7) << 4))) = v;
        }
#pragma unroll
        for (int p = 0; p < 4; ++p) {
          int d = vd + p * 16;
          uint4 v = *reinterpret_cast<const uint4*>(Vh + (size_t)d * T_ + k0 + vkc * 8);
          *reinterpret_cast<uint4*>(Vs + ((d * 256 + vkc * 16) ^ ((d & 7) << 4))) = v;
        }
      }
      __syncthreads();

      // S = Q K^T : 16 q-rows x 128 keys per wave
      f32x4 s[8] = {};
      __builtin_amdgcn_s_setprio(1);
#pragma unroll
      for (int ks = 0; ks < 2; ++ks)
#pragma unroll
        for (int n = 0; n < 8; ++n) {
          bf16x8 bk = ldsAfrag(Ks, n * 16 + lrow, ks * 64 + lgrp * 16);
          s[n] = __builtin_amdgcn_mfma_f32_16x16x32_bf16(qf[ks], bk, s[n], 0, 0, 0);
        }
      __builtin_amdgcn_s_setprio(0);

      // scale (+ causal mask on the diagonal iter only)
      const bool diag = (kt == niter - 1);
#pragma unroll
      for (int n = 0; n < 8; ++n)
#pragma unroll
        for (int r = 0; r < 4; ++r) {
          float v = s[n][r] * 0.125f;
          if (diag) {
            int kg = k0 + n * 16 + lrow;
            int qg = qs + wv * 16 + lgrp * 4 + r;
            v = (kg <= qg) ? v : -__builtin_inff();
          }
          s[n][r] = v;
        }

      // online softmax (rows = lgrp*4+r, 4-step butterfly over lrow)
#pragma unroll
      for (int r = 0; r < 4; ++r) {
        float tm = s[0][r];
#pragma unroll
        for (int n = 1; n < 8; ++n) tm = fmaxf(tm, s[n][r]);
#pragma unroll
        for (int msk = 1; msk < 16; msk <<= 1) tm = fmaxf(tm, __shfl_xor(tm, msk, 64));
        float nm = fmaxf(mrun[r], tm);
        float alpha = __expf(mrun[r] - nm);
        mrun[r] = nm;
        float psum = 0.f;
#pragma unroll
        for (int n = 0; n < 8; ++n) {
          float p = __expf(s[n][r] - nm);
          s[n][r] = p;
          psum += p;
        }
#pragma unroll
        for (int msk = 1; msk < 16; msk <<= 1) psum += __shfl_xor(psum, msk, 64);
        lrun[r] = lrun[r] * alpha + psum;
#pragma unroll
        for (int dn = 0; dn < 4; ++dn) o[dn][r] *= alpha;
      }

      // P -> per-wave LDS (bf16); within-wave write->read, no barrier needed
#pragma unroll
      for (int n = 0; n < 8; ++n)
#pragma unroll
        for (int r = 0; r < 4; ++r) {
          int prow = lgrp * 4 + r;
          int off = (prow * 256 + (n * 16 + lrow) * 2) ^ ((prow & 7) << 4);
          *reinterpret_cast<u16*>(Ps + off) = f2bf(s[n][r]);
        }

      // O += P * V
      __builtin_amdgcn_s_setprio(1);
#pragma unroll
      for (int ks = 0; ks < 4; ++ks) {
        bf16x8 pa = ldsAfrag256(Ps, lrow, ks * 64 + lgrp * 16);
#pragma unroll
        for (int dn = 0; dn < 4; ++dn) {
          bf16x8 bv = ldsAfrag256(Vs, dn * 16 + lrow, ks * 64 + lgrp * 16);
          o[dn] = __builtin_amdgcn_mfma_f32_16x16x32_bf16(pa, bv, o[dn], 0, 0, 0);
        }
      }
      __builtin_amdgcn_s_setprio(0);
    }

    // epilogue for this unit
#pragma unroll
    for (int r = 0; r < 4; ++r) {
      float inv = 1.0f / lrun[r];
      int t = qs + wv * 16 + lgrp * 4 + r;
#pragma unroll
      for (int dn = 0; dn < 4; ++dn) {
        int c = h * HD + dn * 16 + lrow;
        O[((size_t)(b * T_ + t)) * C_ + c] = f2bf(o[dn][r] * inv);
      }
    }
  }
}

// ---------------- launch ----------------
extern "C" void kernel_launch(void* const* d_in, const int* in_sizes, int n_in,
                              void* d_out, int out_size, void* d_ws, size_t ws_size,
                              hipStream_t stream) {
  const float* x  = (const float*)d_in[0];
  const float* wa = (const float*)d_in[1];
  const float* wp = (const float*)d_in[2];
  float* out = (float*)d_out;
  char* ws = (char*)d_ws;
  size_t off = 0;
  auto alloc = [&](size_t bytes) {
    char* p = ws + off;
    off += (bytes + 255) & ~(size_t)255;
    return p;
  };
  u16* xb   = (u16*)alloc((size_t)M_ * C_ * 2);
  u16* wab  = (u16*)alloc((size_t)N3 * C_ * 2);
  u16* wpb  = (u16*)alloc((size_t)C_ * C_ * 2);
  u16* qkvb = (u16*)alloc((size_t)M_ * N3 * 2);
  u16* Qb   = (u16*)alloc((size_t)B_ * H_ * T_ * HD * 2);
  u16* Kb   = (u16*)alloc((size_t)B_ * H_ * T_ * HD * 2);
  u16* Vtb  = (u16*)alloc((size_t)B_ * H_ * T_ * HD * 2);
  u16* Ob   = (u16*)alloc((size_t)M_ * C_ * 2);
  float* cosT = (float*)alloc((size_t)T_ * 32 * 4);
  float* sinT = (float*)alloc((size_t)T_ * 32 * 4);
  (void)in_sizes; (void)n_in; (void)out_size; (void)ws_size;

  cvt_bf16<<<1024, 256, 0, stream>>>(x, xb, M_ * C_ / 4);
  cvt_bf16<<<1024, 256, 0, stream>>>(wa, wab, N3 * C_ / 4);
  cvt_bf16<<<512, 256, 0, stream>>>(wp, wpb, C_ * C_ / 4);
  rope_tables_kernel<<<T_, 32, 0, stream>>>(cosT, sinT);
  gemm_bt<false><<<dim3(M_ / 128, N3 / 128), 256, 0, stream>>>(xb, wab, qkvb, M_, N3, C_);
  rope_reshape<<<dim3(T_ / 64, B_ * H_), 256, 0, stream>>>(qkvb, cosT, sinT, Qb, Kb, Vtb);
  attn_fwd2<<<dim3(16, B_ * H_), 256, 0, stream>>>(Qb, Kb, Vtb, Ob);
  gemm_bt<true><<<dim3(M_ / 128, C_ / 128), 256, 0, stream>>>(Ob, wpb, out, M_, C_, C_);
}